// Round 6
// baseline (59.377 us; speedup 1.0000x reference)
//
#include <hip/hip_runtime.h>

#define S_LEN 1024
#define D_TOT 512
#define D_E   448

typedef short bf16x8 __attribute__((ext_vector_type(8)));
typedef float f32x4  __attribute__((ext_vector_type(4)));
typedef unsigned short u16;

__device__ __forceinline__ float frcp(float x) {
  float r; asm("v_rcp_f32 %0, %1" : "=v"(r) : "v"(x)); return r;
}

__device__ __forceinline__ float wave_sum64(float v) {
#pragma unroll
  for (int o = 32; o > 0; o >>= 1) v += __shfl_xor(v, o);
  return v;
}

__device__ __forceinline__ u16 bf16rne(float f) {
  unsigned u = __builtin_bit_cast(unsigned, f);
  return (u16)((u + 0x7fffu + ((u >> 16) & 1u)) >> 16);
}

// split fp32 into bf16 hi (RNE) + bf16 lo (RNE of remainder)
__device__ __forceinline__ void bsplit(float f, u16 &h, u16 &l) {
  unsigned u  = __builtin_bit_cast(unsigned, f);
  unsigned ur = u + 0x7fffu + ((u >> 16) & 1u);
  h = (u16)(ur >> 16);
  float fh = __builtin_bit_cast(float, ur & 0xffff0000u);
  float r  = f - fh;
  l = bf16rne(r);
}

__device__ __forceinline__ void bsplit8(float4 a, float4 b, uint4 &h, uint4 &l) {
  u16 h0,h1,h2,h3,h4,h5,h6,h7, l0,l1,l2,l3,l4,l5,l6,l7;
  bsplit(a.x,h0,l0); bsplit(a.y,h1,l1); bsplit(a.z,h2,l2); bsplit(a.w,h3,l3);
  bsplit(b.x,h4,l4); bsplit(b.y,h5,l5); bsplit(b.z,h6,l6); bsplit(b.w,h7,l7);
  h.x = (unsigned)h0 | ((unsigned)h1<<16); h.y = (unsigned)h2 | ((unsigned)h3<<16);
  h.z = (unsigned)h4 | ((unsigned)h5<<16); h.w = (unsigned)h6 | ((unsigned)h7<<16);
  l.x = (unsigned)l0 | ((unsigned)l1<<16); l.y = (unsigned)l2 | ((unsigned)l3<<16);
  l.z = (unsigned)l4 | ((unsigned)l5<<16); l.w = (unsigned)l6 | ((unsigned)l7<<16);
}

// 3-term split MFMA: (Ah+Al)(Bh+Bl) ~= AhBh + AhBl + AlBh
#define MFMA3(ACC)                                                                              \
  _Pragma("unroll") for (int i_ = 0; i_ < 2; ++i_)                                              \
  _Pragma("unroll") for (int j_ = 0; j_ < 2; ++j_) {                                            \
    ACC[i_][j_] = __builtin_amdgcn_mfma_f32_16x16x32_bf16(fAh[i_], fBh[j_], ACC[i_][j_],0,0,0); \
    ACC[i_][j_] = __builtin_amdgcn_mfma_f32_16x16x32_bf16(fAh[i_], fBl[j_], ACC[i_][j_],0,0,0); \
    ACC[i_][j_] = __builtin_amdgcn_mfma_f32_16x16x32_bf16(fAl[i_], fBh[j_], ACC[i_][j_],0,0,0); \
  }

// 2-term: A hi-only
#define MFMA2(ACC)                                                                              \
  _Pragma("unroll") for (int i_ = 0; i_ < 2; ++i_)                                              \
  _Pragma("unroll") for (int j_ = 0; j_ < 2; ++j_) {                                            \
    ACC[i_][j_] = __builtin_amdgcn_mfma_f32_16x16x32_bf16(fAh[i_], fBh[j_], ACC[i_][j_],0,0,0); \
    ACC[i_][j_] = __builtin_amdgcn_mfma_f32_16x16x32_bf16(fAh[i_], fBl[j_], ACC[i_][j_],0,0,0); \
  }

#define LD8(p, off) (*(const bf16x8*)((p) + (off)))

// ================= QKV: q/k/v = x @ W.T + b (fp32 in, split in staging) =================
// 64x64 tile, 8 waves = 2(kg) x 2(wr) x 2(wc), BK=32, dbuf LDS, 8 steps.
__global__ __launch_bounds__(512) void qkv_mfma(
    const float* __restrict__ x,
    const float* __restrict__ wq, const float* __restrict__ bq,
    const float* __restrict__ wk, const float* __restrict__ bk,
    const float* __restrict__ wv, const float* __restrict__ bv,
    u16* __restrict__ Qch,
    u16* __restrict__ Kch, u16* __restrict__ Kcl,
    u16* __restrict__ vTh, u16* __restrict__ vTl,
    float* __restrict__ qnpart, float* __restrict__ knpart,
    float* __restrict__ uh2a, float* __restrict__ vh2a)
{
  __shared__ __align__(16) u16 stage[2][20480];   // per buf: [2 kg][Ah|Al|Bh|Bl][64][40]
  float* fbuf = (float*)stage;                    // [2 kg][64][68]
  const int z = blockIdx.z;
  const float* W; const float* bias;
  if (z == 0)      { W = wq; bias = bq; }
  else if (z == 1) { W = wk; bias = bk; }
  else             { W = wv; bias = bv; }
  const int mBase = blockIdx.y << 6, nBase = blockIdx.x << 6;
  const int t = threadIdx.x, lane = t & 63, wave = t >> 6;
  const int kg = t >> 8, sub = t & 255;
  const int srow = sub >> 2, scol = (sub & 3) << 3;
  const int kgw = wave >> 2, wr = (wave >> 1) & 1, wc = wave & 1;

  const float* Ag = x + (size_t)(mBase + srow) * D_TOT + scol + kg * 256;
  const float* Bg = W + (size_t)(nBase + srow) * D_TOT + scol + kg * 256;

  const int sb = kg * 10240 + srow * 40 + scol;
  const int fa = kgw * 10240 + (wr * 32 + (lane & 15)) * 40 + ((lane >> 4) << 3);
  const int fb = kgw * 10240 + (wc * 32 + (lane & 15)) * 40 + ((lane >> 4) << 3);

  float4 a0 = *(const float4*)Ag, a1 = *(const float4*)(Ag + 4);
  float4 b0 = *(const float4*)Bg, b1 = *(const float4*)(Bg + 4);
  {
    uint4 hA,lA,hB,lB;
    bsplit8(a0,a1,hA,lA); bsplit8(b0,b1,hB,lB);
    *(uint4*)&stage[0][sb       ] = hA;
    *(uint4*)&stage[0][sb + 2560] = lA;
    *(uint4*)&stage[0][sb + 5120] = hB;
    *(uint4*)&stage[0][sb + 7680] = lB;
  }
  a0 = *(const float4*)(Ag + 32); a1 = *(const float4*)(Ag + 36);
  b0 = *(const float4*)(Bg + 32); b1 = *(const float4*)(Bg + 36);

  f32x4 zero = {0.f,0.f,0.f,0.f};
  f32x4 acc[2][2] = {{zero,zero},{zero,zero}};
#pragma unroll
  for (int r = 0; r < 8; ++r) {
    __syncthreads();
    const u16* bufr = stage[r & 1];
    bf16x8 fAh[2], fAl[2], fBh[2], fBl[2];
#pragma unroll
    for (int i = 0; i < 2; ++i) {
      fAh[i] = *(const bf16x8*)&bufr[fa        + i*640];
      fAl[i] = *(const bf16x8*)&bufr[fa + 2560 + i*640];
      fBh[i] = *(const bf16x8*)&bufr[fb + 5120 + i*640];
      fBl[i] = *(const bf16x8*)&bufr[fb + 7680 + i*640];
    }
    if (r + 1 < 8) {
      u16* bufw = stage[(r + 1) & 1];
      uint4 hA,lA,hB,lB;
      bsplit8(a0,a1,hA,lA); bsplit8(b0,b1,hB,lB);
      *(uint4*)&bufw[sb       ] = hA;
      *(uint4*)&bufw[sb + 2560] = lA;
      *(uint4*)&bufw[sb + 5120] = hB;
      *(uint4*)&bufw[sb + 7680] = lB;
      if (r + 2 < 8) {
        const int o = (r + 2) * 32;
        a0 = *(const float4*)(Ag + o); a1 = *(const float4*)(Ag + o + 4);
        b0 = *(const float4*)(Bg + o); b1 = *(const float4*)(Bg + o + 4);
      }
    }
    MFMA3(acc);
  }

  // --- cross-kg reduction (single round-trip) ---
  __syncthreads();
  {
    const int r0 = wr*32 + ((lane>>4)<<2);
    const int c0 = wc*32 + (lane&15);
#pragma unroll
    for (int i = 0; i < 2; ++i)
#pragma unroll
      for (int j = 0; j < 2; ++j)
#pragma unroll
        for (int g = 0; g < 4; ++g)
          fbuf[kgw*4352 + (r0 + i*16 + g)*68 + c0 + j*16] = acc[i][j][g];
  }
  __syncthreads();
  const int erow = wave << 3;
  float val[8];
  {
    const float b = bias[nBase + lane];
#pragma unroll
    for (int r = 0; r < 8; ++r)
      val[r] = fbuf[(erow+r)*68 + lane] + fbuf[4352 + (erow+r)*68 + lane] + b;
  }

  // --- epilogue ---
  if (z == 2) {
    u16 hh[8], ll[8];
#pragma unroll
    for (int r = 0; r < 8; ++r) bsplit(val[r], hh[r], ll[r]);
    const size_t off = (size_t)(nBase + lane) * S_LEN + mBase + erow;
    ushort4 p0{hh[0],hh[1],hh[2],hh[3]}, p1{hh[4],hh[5],hh[6],hh[7]};
    ushort4 q0{ll[0],ll[1],ll[2],ll[3]}, q1{ll[4],ll[5],ll[6],ll[7]};
    *(ushort4*)(vTh + off) = p0; *(ushort4*)(vTh + off + 4) = p1;
    *(ushort4*)(vTl + off) = q0; *(ushort4*)(vTl + off + 4) = q1;
  } else if (z == 1) {
    if (blockIdx.x < 7) {
#pragma unroll
      for (int r = 0; r < 8; ++r) {
        const int s = mBase + erow + r;
        u16 h,l; bsplit(val[r],h,l);
        Kch[(size_t)s*D_TOT + nBase + lane] = h;
        Kcl[(size_t)s*D_TOT + nBase + lane] = l;
        float p = wave_sum64(val[r]*val[r]);
        if (lane == 0) knpart[s*8 + blockIdx.x] = p;
      }
    } else {
#pragma unroll
      for (int r = 0; r < 8; ++r) {
        const int s = mBase + erow + r;
        float n2 = wave_sum64(val[r]*val[r]);
        float nn = sqrtf(n2);
        float n  = fmaxf(nn, 1e-5f);
        float e2n = __expf(2.f*n);
        float th  = 1.f - 2.f*frcp(e2n + 1.f);
        float rn  = frcp(n);
        float pn  = th * nn * rn;
        float scale = fminf(0.999f * frcp(fmaxf(pn, 1e-5f)), 1.f);
        float u = th * rn * scale * val[r];
        float un = pn * scale;
        u16 h,l; bsplit(u,h,l);
        Kch[(size_t)s*D_TOT + nBase + lane] = h;
        Kcl[(size_t)s*D_TOT + nBase + lane] = l;
        if (lane == 0) vh2a[s] = un*un;
      }
    }
  } else {
    if (blockIdx.x < 7) {
#pragma unroll
      for (int r = 0; r < 8; ++r) {
        const int s = mBase + erow + r;
        Qch[(size_t)s*D_TOT + nBase + lane] = bf16rne(val[r]);
        float p = wave_sum64(val[r]*val[r]);
        if (lane == 0) qnpart[s*8 + blockIdx.x] = p;
      }
    } else {
#pragma unroll
      for (int r = 0; r < 8; ++r) {
        const int s = mBase + erow + r;
        float n2 = wave_sum64(val[r]*val[r]);
        float nn = sqrtf(n2);
        float n  = fmaxf(nn, 1e-5f);
        float e2n = __expf(2.f*n);
        float th  = 1.f - 2.f*frcp(e2n + 1.f);
        float rn  = frcp(n);
        float pn  = th * nn * rn;
        float scale = fminf(0.999f * frcp(fmaxf(pn, 1e-5f)), 1.f);
        float u = th * rn * scale * val[r];
        float un = pn * scale;
        Qch[(size_t)s*D_TOT + nBase + lane] = bf16rne(u);
        if (lane == 0) uh2a[s] = un*un;
      }
    }
  }
}

// ================= scores: direct-global fragment loads, no K-loop barriers =================
// 64x64 tile, 8 waves = 2(kg) x 2(wr) x 2(wc), each wave 32x32, K split over kg.
__global__ __launch_bounds__(512) void score_mfma(
    const u16* __restrict__ Qch,
    const u16* __restrict__ Kch, const u16* __restrict__ Kcl,
    const float* __restrict__ qnpart, const float* __restrict__ knpart,
    const float* __restrict__ uh2a, const float* __restrict__ vh2a,
    const float* __restrict__ alpha_u,
    u16* __restrict__ Eh, float* __restrict__ rowpart)
{
  __shared__ float fbuf[17408];     // E: [2 kg][64][68] @0; H @8704
  __shared__ float rowscal[256];    // qn[64] kn[64] u2[64] v2[64]
  const int t = threadIdx.x, lane = t & 63, wave = t >> 6;
  const int mBase = blockIdx.y << 6, nBase = blockIdx.x << 6;
  if (t < 64) {
    float s_ = 0.f;
#pragma unroll
    for (int c = 0; c < 7; ++c) s_ += qnpart[(mBase+t)*8 + c];
    rowscal[t] = s_;
  } else if (t < 128) {
    float s_ = 0.f;
#pragma unroll
    for (int c = 0; c < 7; ++c) s_ += knpart[(nBase+t-64)*8 + c];
    rowscal[t] = s_;
  } else if (t < 192) rowscal[t] = uh2a[mBase + t - 128];
  else if (t < 256)   rowscal[t] = vh2a[nBase + t - 192];

  const int kg = wave >> 2, wr = (wave >> 1) & 1, wc = wave & 1;
  const int frow = lane & 15, fk8 = (lane >> 4) << 3;
  const u16* qb  = Qch + (size_t)(mBase + wr*32 + frow) * D_TOT + fk8;
  const u16* kbh = Kch + (size_t)(nBase + wc*32 + frow) * D_TOT + fk8;
  const u16* kbl = Kcl + (size_t)(nBase + wc*32 + frow) * D_TOT + fk8;

  f32x4 zero = {0.f,0.f,0.f,0.f};
  f32x4 accE[2][2] = {{zero,zero},{zero,zero}};
  f32x4 accH[2][2] = {{zero,zero},{zero,zero}};

  int kb0 = kg * 224;
  bf16x8 A0 = LD8(qb, kb0),        A1 = LD8(qb, 8192 + kb0);
  bf16x8 B0h = LD8(kbh, kb0),      B1h = LD8(kbh, 8192 + kb0);
  bf16x8 B0l = LD8(kbl, kb0),      B1l = LD8(kbl, 8192 + kb0);
#pragma unroll
  for (int r = 0; r < 8; ++r) {
    bf16x8 fAh[2] = {A0, A1};
    bf16x8 fBh[2] = {B0h, B1h};
    bf16x8 fBl[2] = {B0l, B1l};
    if (r + 1 < 8) {
      const int o = (r + 1 < 7) ? (kg*224 + (r+1)*32) : (448 + kg*32);
      A0 = LD8(qb, o);   A1 = LD8(qb, 8192 + o);
      B0h = LD8(kbh, o); B1h = LD8(kbh, 8192 + o);
      B0l = LD8(kbl, o); B1l = LD8(kbl, 8192 + o);
    }
    if (r < 7) { MFMA2(accE) } else { MFMA2(accH) }
  }

  // --- single round-trip cross-kg reduction of E and H ---
  __syncthreads();
  {
    const int r0 = wr*32 + ((lane>>4)<<2);
    const int c0 = wc*32 + (lane&15);
#pragma unroll
    for (int i = 0; i < 2; ++i)
#pragma unroll
      for (int j = 0; j < 2; ++j)
#pragma unroll
        for (int g = 0; g < 4; ++g) {
          fbuf[       kg*4352 + (r0 + i*16 + g)*68 + c0 + j*16] = accE[i][j][g];
          fbuf[8704 + kg*4352 + (r0 + i*16 + g)*68 + c0 + j*16] = accH[i][j][g];
        }
  }
  __syncthreads();
  const int erow = wave << 3;
  float eE[8], eH[8];
#pragma unroll
  for (int r = 0; r < 8; ++r) {
    eE[r] = fbuf[(erow+r)*68 + lane] + fbuf[4352 + (erow+r)*68 + lane];
    eH[r] = fbuf[8704 + (erow+r)*68 + lane] + fbuf[8704 + 4352 + (erow+r)*68 + lane];
  }

  // --- transcendental epilogue ---
  const float alpha = __logf(1.f + __expf(alpha_u[0]));
  const float inv_s = 0.04419417382415922f;   // 1/sqrt(512)
  const float knl = rowscal[64 + lane], v2 = rowscal[192 + lane];
#pragma unroll
  for (int r = 0; r < 8; ++r) {
    const int s = mBase + erow + r;
    const float qns = rowscal[erow + r], u2 = rowscal[128 + erow + r];
    float de   = qns + knl - 2.f * eE[r];
    float dH   = eH[r];
    float Ac   = 1.f - 2.f*dH + v2;
    float Bc   = 1.f - u2;
    float num2 = Ac*Ac*u2 + Bc*Bc*v2 - 2.f*Ac*Bc*dH;
    float den  = fmaxf(1.f - 2.f*dH + u2*v2, 1e-5f);
    float frac = sqrtf(fmaxf(num2, 0.f)) * frcp(den);
    float nrm  = fminf(frac, 0.999f);
    float dh_  = __logf((1.f + nrm) * frcp(1.f - nrm));   // = 2*atanh(nrm)
    float dist = de + alpha * dh_ * dh_;
    float lg   = fminf(fmaxf(-dist * inv_s, -50.f), 0.f);
    float e    = __expf(lg);
    Eh[(size_t)s*S_LEN + nBase + lane] = bf16rne(e);
    float rs = wave_sum64(e);
    if (lane == 0) rowpart[s*16 + blockIdx.x] = rs;
  }
}

// ================= attn @ V: direct-global loads =================
// 32x64 tile, 8 waves = 4(kg) x 2(wc), each wave 32x32, K=1024 split over kg.
__global__ __launch_bounds__(512) void av_mfma(
    const u16* __restrict__ Eh,
    const u16* __restrict__ vTh, const u16* __restrict__ vTl,
    const float* __restrict__ rowpart,
    u16* __restrict__ out1h, u16* __restrict__ out1l)
{
  __shared__ float fbuf[8704];    // [4 kg][32][68]
  __shared__ float rinvl[32];
  const int t = threadIdx.x, lane = t & 63, wave = t >> 6;
  const int mBase = blockIdx.y << 5, nBase = blockIdx.x << 6;
  if (t < 32) {
    float s_ = 0.f;
#pragma unroll
    for (int c = 0; c < 16; ++c) s_ += rowpart[(mBase+t)*16 + c];
    rinvl[t] = 1.f / s_;
  }
  const int kg = wave >> 1, wc = wave & 1;
  const int frow = lane & 15, fk8 = (lane >> 4) << 3;
  const u16* eb  = Eh  + (size_t)(mBase + frow) * S_LEN + fk8 + kg*256;
  const u16* vbh = vTh + (size_t)(nBase + wc*32 + frow) * S_LEN + fk8 + kg*256;
  const u16* vbl = vTl + (size_t)(nBase + wc*32 + frow) * S_LEN + fk8 + kg*256;

  f32x4 zero = {0.f,0.f,0.f,0.f};
  f32x4 acc[2][2] = {{zero,zero},{zero,zero}};

  bf16x8 A0 = LD8(eb, 0),   A1 = LD8(eb, 16384);
  bf16x8 B0h = LD8(vbh, 0), B1h = LD8(vbh, 16384);
  bf16x8 B0l = LD8(vbl, 0), B1l = LD8(vbl, 16384);
#pragma unroll
  for (int r = 0; r < 8; ++r) {
    bf16x8 fAh[2] = {A0, A1};
    bf16x8 fBh[2] = {B0h, B1h};
    bf16x8 fBl[2] = {B0l, B1l};
    if (r + 1 < 8) {
      const int o = (r + 1) * 32;
      A0 = LD8(eb, o);   A1 = LD8(eb, 16384 + o);
      B0h = LD8(vbh, o); B1h = LD8(vbh, 16384 + o);
      B0l = LD8(vbl, o); B1l = LD8(vbl, 16384 + o);
    }
    MFMA2(acc);
  }

  __syncthreads();
  {
    const int r0 = (lane>>4)<<2;
    const int c0 = wc*32 + (lane&15);
#pragma unroll
    for (int i = 0; i < 2; ++i)
#pragma unroll
      for (int j = 0; j < 2; ++j)
#pragma unroll
        for (int g = 0; g < 4; ++g)
          fbuf[kg*2176 + (r0 + i*16 + g)*68 + c0 + j*16] = acc[i][j][g];
  }
  __syncthreads();
  const int erow = wave << 2;
#pragma unroll
  for (int r = 0; r < 4; ++r) {
    const int row = erow + r;
    float e = fbuf[row*68 + lane] + fbuf[2176 + row*68 + lane]
            + fbuf[4352 + row*68 + lane] + fbuf[6528 + row*68 + lane];
    float v_ = e * rinvl[row];
    u16 h,l; bsplit(v_,h,l);
    const int s = mBase + row;
    out1h[(size_t)s*D_TOT + nBase + lane] = h;
    out1l[(size_t)s*D_TOT + nBase + lane] = l;
  }
}

// ================= final: out = out1 @ wo.T + bo (wo fp32 split in-reg) =================
// 32x64 tile, 8 waves = 4(kg) x 2(wc), K=512 split over kg (4 steps each).
__global__ __launch_bounds__(512) void final_mfma(
    const u16* __restrict__ out1h, const u16* __restrict__ out1l,
    const float* __restrict__ wo, const float* __restrict__ bo,
    float* __restrict__ out)
{
  __shared__ float fbuf[8704];    // [4 kg][32][68]
  const int t = threadIdx.x, lane = t & 63, wave = t >> 6;
  const int mBase = blockIdx.y << 5, nBase = blockIdx.x << 6;
  const int kg = wave >> 1, wc = wave & 1;
  const int frow = lane & 15, fk8 = (lane >> 4) << 3;
  const u16*   ah = out1h + (size_t)(mBase + frow) * D_TOT + fk8 + kg*128;
  const u16*   al = out1l + (size_t)(mBase + frow) * D_TOT + fk8 + kg*128;
  const float* wb = wo + (size_t)(nBase + wc*32 + frow) * D_TOT + fk8 + kg*128;

  f32x4 zero = {0.f,0.f,0.f,0.f};
  f32x4 acc[2][2] = {{zero,zero},{zero,zero}};

  bf16x8 A0h = LD8(ah, 0), A1h = LD8(ah, 8192);
  bf16x8 A0l = LD8(al, 0), A1l = LD8(al, 8192);
  float4 w00 = *(const float4*)wb,          w01 = *(const float4*)(wb + 4);
  float4 w10 = *(const float4*)(wb + 8192), w11 = *(const float4*)(wb + 8196);
#pragma unroll
  for (int r = 0; r < 4; ++r) {
    bf16x8 fAh[2] = {A0h, A1h};
    bf16x8 fAl[2] = {A0l, A1l};
    bf16x8 fBh[2], fBl[2];
    {
      uint4 h0,l0,h1,l1;
      bsplit8(w00, w01, h0, l0); bsplit8(w10, w11, h1, l1);
      fBh[0] = __builtin_bit_cast(bf16x8, h0); fBl[0] = __builtin_bit_cast(bf16x8, l0);
      fBh[1] = __builtin_bit_cast(bf16x8, h1); fBl[1] = __builtin_bit_cast(bf16x8, l1);
    }
    if (r + 1 < 4) {
      const int o = (r + 1) * 32;
      A0h = LD8(ah, o); A1h = LD8(ah, 8192 + o);
      A0l = LD8(al, o); A1l = LD8(al, 8192 + o);
      w00 = *(const float4*)(wb + o);        w01 = *(const float4*)(wb + o + 4);
      w10 = *(const float4*)(wb + 8192 + o); w11 = *(const float4*)(wb + 8196 + o);
    }
    MFMA3(acc);
  }

  __syncthreads();
  {
    const int r0 = (lane>>4)<<2;
    const int c0 = wc*32 + (lane&15);
#pragma unroll
    for (int i = 0; i < 2; ++i)
#pragma unroll
      for (int j = 0; j < 2; ++j)
#pragma unroll
        for (int g = 0; g < 4; ++g)
          fbuf[kg*2176 + (r0 + i*16 + g)*68 + c0 + j*16] = acc[i][j][g];
  }
  __syncthreads();
  const int erow = wave << 2;
  const float b = bo[nBase + lane];
#pragma unroll
  for (int r = 0; r < 4; ++r) {
    const int row = erow + r;
    float e = fbuf[row*68 + lane] + fbuf[2176 + row*68 + lane]
            + fbuf[4352 + row*68 + lane] + fbuf[6528 + row*68 + lane];
    out[(size_t)(mBase+row)*D_TOT + nBase + lane] = e + b;
  }
}

extern "C" void kernel_launch(void* const* d_in, const int* in_sizes, int n_in,
                              void* d_out, int out_size, void* d_ws, size_t ws_size,
                              hipStream_t stream)
{
  const float* x   = (const float*)d_in[0];
  const float* wq  = (const float*)d_in[1];
  const float* bq  = (const float*)d_in[2];
  const float* wk  = (const float*)d_in[3];
  const float* bk  = (const float*)d_in[4];
  const float* wv  = (const float*)d_in[5];
  const float* bv  = (const float*)d_in[6];
  const float* wo  = (const float*)d_in[7];
  const float* bo  = (const float*)d_in[8];
  const float* alpha_u = (const float*)d_in[9];
  float* out = (float*)d_out;

  u16* U = (u16*)d_ws;
  u16* Qch   = U + 0;
  u16* Kch   = U + 524288;
  u16* Kcl   = U + 1048576;
  u16* vTh   = U + 1572864;
  u16* vTl   = U + 2097152;
  u16* Eh    = U + 2621440;   // 1048576
  u16* out1h = U + 3670016;
  u16* out1l = U + 4194304;
  float* F = (float*)(U + 4718592);
  float* qnpart  = F;          // [1024][8]
  float* knpart  = F + 8192;
  float* uh2a    = F + 16384;
  float* vh2a    = F + 17408;
  float* rowpart = F + 18432;  // [1024][16]

  qkv_mfma<<<dim3(8,16,3), 512, 0, stream>>>(x, wq,bq, wk,bk, wv,bv,
      Qch, Kch, Kcl, vTh, vTl, qnpart, knpart, uh2a, vh2a);
  score_mfma<<<dim3(16,16), 512, 0, stream>>>(Qch, Kch, Kcl,
      qnpart, knpart, uh2a, vh2a, alpha_u, Eh, rowpart);
  av_mfma<<<dim3(8,32), 512, 0, stream>>>(Eh, vTh, vTl, rowpart, out1h, out1l);
  final_mfma<<<dim3(8,32), 512, 0, stream>>>(out1h, out1l, wo, bo, out);
}

// Round 7
// 49.854 us; speedup vs baseline: 1.1910x; 1.1910x over previous
//
#include <hip/hip_runtime.h>

#define S_LEN 1024
#define D_TOT 512
#define D_E   448

typedef short bf16x8 __attribute__((ext_vector_type(8)));
typedef float f32x4  __attribute__((ext_vector_type(4)));
typedef unsigned short u16;

__device__ __forceinline__ float frcp(float x) {
  float r; asm("v_rcp_f32 %0, %1" : "=v"(r) : "v"(x)); return r;
}

__device__ __forceinline__ float wave_sum64(float v) {
#pragma unroll
  for (int o = 32; o > 0; o >>= 1) v += __shfl_xor(v, o);
  return v;
}

__device__ __forceinline__ u16 bf16rne(float f) {
  unsigned u = __builtin_bit_cast(unsigned, f);
  return (u16)((u + 0x7fffu + ((u >> 16) & 1u)) >> 16);
}

// split fp32 into bf16 hi (RNE) + bf16 lo (RNE of remainder)
__device__ __forceinline__ void bsplit(float f, u16 &h, u16 &l) {
  unsigned u  = __builtin_bit_cast(unsigned, f);
  unsigned ur = u + 0x7fffu + ((u >> 16) & 1u);
  h = (u16)(ur >> 16);
  float fh = __builtin_bit_cast(float, ur & 0xffff0000u);
  float r  = f - fh;
  l = bf16rne(r);
}

__device__ __forceinline__ void bsplit8(float4 a, float4 b, uint4 &h, uint4 &l) {
  u16 h0,h1,h2,h3,h4,h5,h6,h7, l0,l1,l2,l3,l4,l5,l6,l7;
  bsplit(a.x,h0,l0); bsplit(a.y,h1,l1); bsplit(a.z,h2,l2); bsplit(a.w,h3,l3);
  bsplit(b.x,h4,l4); bsplit(b.y,h5,l5); bsplit(b.z,h6,l6); bsplit(b.w,h7,l7);
  h.x = (unsigned)h0 | ((unsigned)h1<<16); h.y = (unsigned)h2 | ((unsigned)h3<<16);
  h.z = (unsigned)h4 | ((unsigned)h5<<16); h.w = (unsigned)h6 | ((unsigned)h7<<16);
  l.x = (unsigned)l0 | ((unsigned)l1<<16); l.y = (unsigned)l2 | ((unsigned)l3<<16);
  l.z = (unsigned)l4 | ((unsigned)l5<<16); l.w = (unsigned)l6 | ((unsigned)l7<<16);
}

// 3-term split MFMA: (Ah+Al)(Bh+Bl) ~= AhBh + AhBl + AlBh
#define MFMA3(ACC)                                                                              \
  _Pragma("unroll") for (int i_ = 0; i_ < 2; ++i_)                                              \
  _Pragma("unroll") for (int j_ = 0; j_ < 2; ++j_) {                                            \
    ACC[i_][j_] = __builtin_amdgcn_mfma_f32_16x16x32_bf16(fAh[i_], fBh[j_], ACC[i_][j_],0,0,0); \
    ACC[i_][j_] = __builtin_amdgcn_mfma_f32_16x16x32_bf16(fAh[i_], fBl[j_], ACC[i_][j_],0,0,0); \
    ACC[i_][j_] = __builtin_amdgcn_mfma_f32_16x16x32_bf16(fAl[i_], fBh[j_], ACC[i_][j_],0,0,0); \
  }

// 2-term: A hi-only
#define MFMA2(ACC)                                                                              \
  _Pragma("unroll") for (int i_ = 0; i_ < 2; ++i_)                                              \
  _Pragma("unroll") for (int j_ = 0; j_ < 2; ++j_) {                                            \
    ACC[i_][j_] = __builtin_amdgcn_mfma_f32_16x16x32_bf16(fAh[i_], fBh[j_], ACC[i_][j_],0,0,0); \
    ACC[i_][j_] = __builtin_amdgcn_mfma_f32_16x16x32_bf16(fAh[i_], fBl[j_], ACC[i_][j_],0,0,0); \
  }

// ================= QKV: q/k/v = x @ W.T + b (fp32 in, split in staging) =================
// 64x64 tile, 8 waves = 2(kg) x 2(wr) x 2(wc), BK=32, dbuf LDS, 8 steps.  (round-5 verbatim)
__global__ __launch_bounds__(512) void qkv_mfma(
    const float* __restrict__ x,
    const float* __restrict__ wq, const float* __restrict__ bq,
    const float* __restrict__ wk, const float* __restrict__ bk,
    const float* __restrict__ wv, const float* __restrict__ bv,
    u16* __restrict__ Qch,
    u16* __restrict__ Kch, u16* __restrict__ Kcl,
    u16* __restrict__ vTh, u16* __restrict__ vTl,
    float* __restrict__ qnpart, float* __restrict__ knpart,
    float* __restrict__ uh2a, float* __restrict__ vh2a)
{
  __shared__ __align__(16) u16 stage[2][20480];   // per buf: [2 kg][Ah|Al|Bh|Bl][64][40]
  float* fbuf = (float*)stage;                    // [2 kg][64][68]
  const int z = blockIdx.z;
  const float* W; const float* bias;
  if (z == 0)      { W = wq; bias = bq; }
  else if (z == 1) { W = wk; bias = bk; }
  else             { W = wv; bias = bv; }
  const int mBase = blockIdx.y << 6, nBase = blockIdx.x << 6;
  const int t = threadIdx.x, lane = t & 63, wave = t >> 6;
  const int kg = t >> 8, sub = t & 255;
  const int srow = sub >> 2, scol = (sub & 3) << 3;
  const int kgw = wave >> 2, wr = (wave >> 1) & 1, wc = wave & 1;

  const float* Ag = x + (size_t)(mBase + srow) * D_TOT + scol + kg * 256;
  const float* Bg = W + (size_t)(nBase + srow) * D_TOT + scol + kg * 256;

  const int sb = kg * 10240 + srow * 40 + scol;
  const int fa = kgw * 10240 + (wr * 32 + (lane & 15)) * 40 + ((lane >> 4) << 3);
  const int fb = kgw * 10240 + (wc * 32 + (lane & 15)) * 40 + ((lane >> 4) << 3);

  float4 a0 = *(const float4*)Ag, a1 = *(const float4*)(Ag + 4);
  float4 b0 = *(const float4*)Bg, b1 = *(const float4*)(Bg + 4);
  {
    uint4 hA,lA,hB,lB;
    bsplit8(a0,a1,hA,lA); bsplit8(b0,b1,hB,lB);
    *(uint4*)&stage[0][sb       ] = hA;
    *(uint4*)&stage[0][sb + 2560] = lA;
    *(uint4*)&stage[0][sb + 5120] = hB;
    *(uint4*)&stage[0][sb + 7680] = lB;
  }
  a0 = *(const float4*)(Ag + 32); a1 = *(const float4*)(Ag + 36);
  b0 = *(const float4*)(Bg + 32); b1 = *(const float4*)(Bg + 36);

  f32x4 zero = {0.f,0.f,0.f,0.f};
  f32x4 acc[2][2] = {{zero,zero},{zero,zero}};
#pragma unroll
  for (int r = 0; r < 8; ++r) {
    __syncthreads();
    const u16* bufr = stage[r & 1];
    bf16x8 fAh[2], fAl[2], fBh[2], fBl[2];
#pragma unroll
    for (int i = 0; i < 2; ++i) {
      fAh[i] = *(const bf16x8*)&bufr[fa        + i*640];
      fAl[i] = *(const bf16x8*)&bufr[fa + 2560 + i*640];
      fBh[i] = *(const bf16x8*)&bufr[fb + 5120 + i*640];
      fBl[i] = *(const bf16x8*)&bufr[fb + 7680 + i*640];
    }
    if (r + 1 < 8) {
      u16* bufw = stage[(r + 1) & 1];
      uint4 hA,lA,hB,lB;
      bsplit8(a0,a1,hA,lA); bsplit8(b0,b1,hB,lB);
      *(uint4*)&bufw[sb       ] = hA;
      *(uint4*)&bufw[sb + 2560] = lA;
      *(uint4*)&bufw[sb + 5120] = hB;
      *(uint4*)&bufw[sb + 7680] = lB;
      if (r + 2 < 8) {
        const int o = (r + 2) * 32;
        a0 = *(const float4*)(Ag + o); a1 = *(const float4*)(Ag + o + 4);
        b0 = *(const float4*)(Bg + o); b1 = *(const float4*)(Bg + o + 4);
      }
    }
    MFMA3(acc);
  }

  __syncthreads();
  {
    const int r0 = wr*32 + ((lane>>4)<<2);
    const int c0 = wc*32 + (lane&15);
#pragma unroll
    for (int i = 0; i < 2; ++i)
#pragma unroll
      for (int j = 0; j < 2; ++j)
#pragma unroll
        for (int g = 0; g < 4; ++g)
          fbuf[kgw*4352 + (r0 + i*16 + g)*68 + c0 + j*16] = acc[i][j][g];
  }
  __syncthreads();
  const int erow = wave << 3;
  float val[8];
  {
    const float b = bias[nBase + lane];
#pragma unroll
    for (int r = 0; r < 8; ++r)
      val[r] = fbuf[(erow+r)*68 + lane] + fbuf[4352 + (erow+r)*68 + lane] + b;
  }

  if (z == 2) {
    u16 hh[8], ll[8];
#pragma unroll
    for (int r = 0; r < 8; ++r) bsplit(val[r], hh[r], ll[r]);
    const size_t off = (size_t)(nBase + lane) * S_LEN + mBase + erow;
    ushort4 p0{hh[0],hh[1],hh[2],hh[3]}, p1{hh[4],hh[5],hh[6],hh[7]};
    ushort4 q0{ll[0],ll[1],ll[2],ll[3]}, q1{ll[4],ll[5],ll[6],ll[7]};
    *(ushort4*)(vTh + off) = p0; *(ushort4*)(vTh + off + 4) = p1;
    *(ushort4*)(vTl + off) = q0; *(ushort4*)(vTl + off + 4) = q1;
  } else if (z == 1) {
    if (blockIdx.x < 7) {
#pragma unroll
      for (int r = 0; r < 8; ++r) {
        const int s = mBase + erow + r;
        u16 h,l; bsplit(val[r],h,l);
        Kch[(size_t)s*D_TOT + nBase + lane] = h;
        Kcl[(size_t)s*D_TOT + nBase + lane] = l;
        float p = wave_sum64(val[r]*val[r]);
        if (lane == 0) knpart[s*8 + blockIdx.x] = p;
      }
    } else {
#pragma unroll
      for (int r = 0; r < 8; ++r) {
        const int s = mBase + erow + r;
        float n2 = wave_sum64(val[r]*val[r]);
        float nn = sqrtf(n2);
        float n  = fmaxf(nn, 1e-5f);
        float e2n = __expf(2.f*n);
        float th  = 1.f - 2.f*frcp(e2n + 1.f);
        float rn  = frcp(n);
        float pn  = th * nn * rn;
        float scale = fminf(0.999f * frcp(fmaxf(pn, 1e-5f)), 1.f);
        float u = th * rn * scale * val[r];
        float un = pn * scale;
        u16 h,l; bsplit(u,h,l);
        Kch[(size_t)s*D_TOT + nBase + lane] = h;
        Kcl[(size_t)s*D_TOT + nBase + lane] = l;
        if (lane == 0) vh2a[s] = un*un;
      }
    }
  } else {
    if (blockIdx.x < 7) {
#pragma unroll
      for (int r = 0; r < 8; ++r) {
        const int s = mBase + erow + r;
        Qch[(size_t)s*D_TOT + nBase + lane] = bf16rne(val[r]);
        float p = wave_sum64(val[r]*val[r]);
        if (lane == 0) qnpart[s*8 + blockIdx.x] = p;
      }
    } else {
#pragma unroll
      for (int r = 0; r < 8; ++r) {
        const int s = mBase + erow + r;
        float n2 = wave_sum64(val[r]*val[r]);
        float nn = sqrtf(n2);
        float n  = fmaxf(nn, 1e-5f);
        float e2n = __expf(2.f*n);
        float th  = 1.f - 2.f*frcp(e2n + 1.f);
        float rn  = frcp(n);
        float pn  = th * nn * rn;
        float scale = fminf(0.999f * frcp(fmaxf(pn, 1e-5f)), 1.f);
        float u = th * rn * scale * val[r];
        float un = pn * scale;
        Qch[(size_t)s*D_TOT + nBase + lane] = bf16rne(u);
        if (lane == 0) uh2a[s] = un*un;
      }
    }
  }
}

// ================= scores: 32x64 tile, grid 512, single-buf, 2 blocks/CU =================
// 8 waves = 4(kg: K=128 each) x 2(wc). 4 steps of BK=32 per kg.
__global__ __launch_bounds__(512) void score_mfma(
    const u16* __restrict__ Qch,
    const u16* __restrict__ Kch, const u16* __restrict__ Kcl,
    const float* __restrict__ qnpart, const float* __restrict__ knpart,
    const float* __restrict__ uh2a, const float* __restrict__ vh2a,
    const float* __restrict__ alpha_u,
    u16* __restrict__ Eh, float* __restrict__ rowpart)
{
  // staging: A(hi) [4][32][40] + Bh [4][64][40] + Bl [4][64][40] = 25600 u16 = 51200 B
  // fbuf overlay: E [4][32][68] + H [32][68] = 10880 f = 43520 B
  __shared__ __align__(16) char shm_[51200];
  __shared__ float rowscal[192];   // qn[0..31] kn[32..95] u2[96..127] v2[128..191]
  u16* stg = (u16*)shm_;
  float* fbuf = (float*)shm_;
  const int t = threadIdx.x, lane = t & 63, wave = t >> 6;
  const int mBase = blockIdx.y << 5, nBase = blockIdx.x << 6;
  if (t < 32) {
    float s_ = 0.f;
#pragma unroll
    for (int c = 0; c < 7; ++c) s_ += qnpart[(mBase+t)*8 + c];
    rowscal[t] = s_;
  } else if (t < 96) {
    float s_ = 0.f;
#pragma unroll
    for (int c = 0; c < 7; ++c) s_ += knpart[(nBase+t-32)*8 + c];
    rowscal[t] = s_;
  } else if (t < 128) rowscal[t] = uh2a[mBase + t - 96];
  else if (t < 192)   rowscal[t] = vh2a[nBase + t - 128];

  const int kg = t >> 7, sub = t & 127;
  const int wc = wave & 1;
  const int frow = lane & 15, fk8 = (lane >> 4) << 3;

  // staging source addresses
  const int arow = sub >> 2, acol8 = (sub & 3) << 3;
  const int brow0 = sub >> 2, brow1 = 32 + (sub >> 2), bcol8 = (sub & 3) << 3;
  const u16* Aq  = Qch + (size_t)(mBase + arow) * D_TOT + kg*128 + acol8;
  const u16* Bh0 = Kch + (size_t)(nBase + brow0) * D_TOT + kg*128 + bcol8;
  const u16* Bh1 = Kch + (size_t)(nBase + brow1) * D_TOT + kg*128 + bcol8;
  const u16* Bl0 = Kcl + (size_t)(nBase + brow0) * D_TOT + kg*128 + bcol8;
  const u16* Bl1 = Kcl + (size_t)(nBase + brow1) * D_TOT + kg*128 + bcol8;

  const int sA  = kg*1280 + arow*40 + acol8;
  const int sB0 = 5120  + kg*2560 + brow0*40 + bcol8;
  const int sB1 = 5120  + kg*2560 + brow1*40 + bcol8;
  const int sL0 = 15360 + kg*2560 + brow0*40 + bcol8;
  const int sL1 = 15360 + kg*2560 + brow1*40 + bcol8;
  const int fa  = kg*1280 + frow*40 + fk8;
  const int fbh = 5120  + kg*2560 + (wc*32 + frow)*40 + fk8;
  const int fbl = 15360 + kg*2560 + (wc*32 + frow)*40 + fk8;

  uint4 rA  = *(const uint4*)Aq;
  uint4 rb0 = *(const uint4*)Bh0, rb1 = *(const uint4*)Bh1;
  uint4 rl0 = *(const uint4*)Bl0, rl1 = *(const uint4*)Bl1;

  f32x4 zero = {0.f,0.f,0.f,0.f};
  f32x4 accE[2][2] = {{zero,zero},{zero,zero}};
  f32x4 accH[2][2] = {{zero,zero},{zero,zero}};
#pragma unroll
  for (int r = 0; r < 4; ++r) {
    __syncthreads();
    *(uint4*)&stg[sA ] = rA;
    *(uint4*)&stg[sB0] = rb0; *(uint4*)&stg[sB1] = rb1;
    *(uint4*)&stg[sL0] = rl0; *(uint4*)&stg[sL1] = rl1;
    if (r + 1 < 4) {
      const int o = (r + 1) * 32;
      rA  = *(const uint4*)(Aq + o);
      rb0 = *(const uint4*)(Bh0 + o); rb1 = *(const uint4*)(Bh1 + o);
      rl0 = *(const uint4*)(Bl0 + o); rl1 = *(const uint4*)(Bl1 + o);
    }
    __syncthreads();
    bf16x8 fAh[2], fBh[2], fBl[2];
#pragma unroll
    for (int i = 0; i < 2; ++i) {
      fAh[i] = *(const bf16x8*)&stg[fa  + i*640];
      fBh[i] = *(const bf16x8*)&stg[fbh + i*640];
      fBl[i] = *(const bf16x8*)&stg[fbl + i*640];
    }
    if (kg < 3 || r < 2) { MFMA2(accE) } else { MFMA2(accH) }
  }

  // --- cross-kg reduction: E partials [4][32][68] @0, H partial [32][68] @8704 ---
  __syncthreads();
  {
    const int r0 = (lane>>4)<<2;
    const int c0 = wc*32 + (lane&15);
#pragma unroll
    for (int i = 0; i < 2; ++i)
#pragma unroll
      for (int j = 0; j < 2; ++j)
#pragma unroll
        for (int g = 0; g < 4; ++g) {
          fbuf[kg*2176 + (i*16 + r0 + g)*68 + c0 + j*16] = accE[i][j][g];
          if (kg == 3)
            fbuf[8704 + (i*16 + r0 + g)*68 + c0 + j*16] = accH[i][j][g];
        }
  }
  __syncthreads();

  // --- transcendental epilogue: 8 waves x 4 rows, 64 cols per lane ---
  const float alpha = __logf(1.f + __expf(alpha_u[0]));
  const float inv_s = 0.04419417382415922f;   // 1/sqrt(512)
  const float knl = rowscal[32 + lane], v2 = rowscal[128 + lane];
#pragma unroll
  for (int rr = 0; rr < 4; ++rr) {
    const int row = (wave << 2) + rr;
    const int s = mBase + row;
    float eE = fbuf[row*68 + lane] + fbuf[2176 + row*68 + lane]
             + fbuf[4352 + row*68 + lane] + fbuf[6528 + row*68 + lane];
    float dH = fbuf[8704 + row*68 + lane];
    const float qns = rowscal[row], u2 = rowscal[96 + row];
    float de   = qns + knl - 2.f * eE;
    float Ac   = 1.f - 2.f*dH + v2;
    float Bc   = 1.f - u2;
    float num2 = Ac*Ac*u2 + Bc*Bc*v2 - 2.f*Ac*Bc*dH;
    float den  = fmaxf(1.f - 2.f*dH + u2*v2, 1e-5f);
    float frac = sqrtf(fmaxf(num2, 0.f)) * frcp(den);
    float nrm  = fminf(frac, 0.999f);
    float dh_  = __logf((1.f + nrm) * frcp(1.f - nrm));   // = 2*atanh(nrm)
    float dist = de + alpha * dh_ * dh_;
    float lg   = fminf(fmaxf(-dist * inv_s, -50.f), 0.f);
    float e    = __expf(lg);
    Eh[(size_t)s*S_LEN + nBase + lane] = bf16rne(e);
    float rs = wave_sum64(e);
    if (lane == 0) rowpart[s*16 + blockIdx.x] = rs;
  }
}

// ================= attn @ V: 32x32 tile, grid 512, single-buf, 2 blocks/CU =================
// 8 waves = 8 kg (K=128 each), each wave full 32x32, 4 steps of BK=32.
__global__ __launch_bounds__(512) void av_mfma(
    const u16* __restrict__ Eh,
    const u16* __restrict__ vTh, const u16* __restrict__ vTl,
    const float* __restrict__ rowpart,
    u16* __restrict__ out1h, u16* __restrict__ out1l)
{
  // staging: A(E hi) [8][32][40] + Bh [8][32][40] + Bl [8][32][40] = 30720 u16 = 61440 B
  // fbuf overlay: [8][32][36] f = 9216 f = 36864 B
  __shared__ __align__(16) char shm_[61440];
  __shared__ float rinvl[32];
  u16* stg = (u16*)shm_;
  float* fbuf = (float*)shm_;
  const int t = threadIdx.x, lane = t & 63, wave = t >> 6;
  const int mBase = blockIdx.y << 5, nBase = blockIdx.x << 5;
  if (t < 32) {
    float s_ = 0.f;
#pragma unroll
    for (int c = 0; c < 16; ++c) s_ += rowpart[(mBase+t)*16 + c];
    rinvl[t] = 1.f / s_;
  }
  const int kg = wave;
  const int frow = lane & 15, fk8 = (lane >> 4) << 3;

  // staging: per wave, per step: A 32x32, Bh 32x32, Bl 32x32; 2 chunks each per lane
  const int r0c = lane >> 2,  c0c = (lane & 3) << 3;        // chunk 0: rows 0..15
  const int r1c = 16 + (lane >> 2);                          // chunk 1: rows 16..31
  const u16* Ae0 = Eh  + (size_t)(mBase + r0c) * S_LEN + kg*128 + c0c;
  const u16* Ae1 = Eh  + (size_t)(mBase + r1c) * S_LEN + kg*128 + c0c;
  const u16* Vh0 = vTh + (size_t)(nBase + r0c) * S_LEN + kg*128 + c0c;
  const u16* Vh1 = vTh + (size_t)(nBase + r1c) * S_LEN + kg*128 + c0c;
  const u16* Vl0 = vTl + (size_t)(nBase + r0c) * S_LEN + kg*128 + c0c;
  const u16* Vl1 = vTl + (size_t)(nBase + r1c) * S_LEN + kg*128 + c0c;

  const int sA0 = kg*1280 + r0c*40 + c0c,          sA1 = kg*1280 + r1c*40 + c0c;
  const int sH0 = 10240 + kg*1280 + r0c*40 + c0c,  sH1 = 10240 + kg*1280 + r1c*40 + c0c;
  const int sL0 = 20480 + kg*1280 + r0c*40 + c0c,  sL1 = 20480 + kg*1280 + r1c*40 + c0c;
  const int fa  = kg*1280 + frow*40 + fk8;
  const int fbh = 10240 + kg*1280 + frow*40 + fk8;
  const int fbl = 20480 + kg*1280 + frow*40 + fk8;

  uint4 ra0 = *(const uint4*)Ae0, ra1 = *(const uint4*)Ae1;
  uint4 rh0 = *(const uint4*)Vh0, rh1 = *(const uint4*)Vh1;
  uint4 rl0 = *(const uint4*)Vl0, rl1 = *(const uint4*)Vl1;

  f32x4 zero = {0.f,0.f,0.f,0.f};
  f32x4 acc[2][2] = {{zero,zero},{zero,zero}};
#pragma unroll
  for (int r = 0; r < 4; ++r) {
    __syncthreads();
    *(uint4*)&stg[sA0] = ra0; *(uint4*)&stg[sA1] = ra1;
    *(uint4*)&stg[sH0] = rh0; *(uint4*)&stg[sH1] = rh1;
    *(uint4*)&stg[sL0] = rl0; *(uint4*)&stg[sL1] = rl1;
    if (r + 1 < 4) {
      const int o = (r + 1) * 32;
      ra0 = *(const uint4*)(Ae0 + o); ra1 = *(const uint4*)(Ae1 + o);
      rh0 = *(const uint4*)(Vh0 + o); rh1 = *(const uint4*)(Vh1 + o);
      rl0 = *(const uint4*)(Vl0 + o); rl1 = *(const uint4*)(Vl1 + o);
    }
    __syncthreads();
    bf16x8 fAh[2], fBh[2], fBl[2];
#pragma unroll
    for (int i = 0; i < 2; ++i) {
      fAh[i] = *(const bf16x8*)&stg[fa  + i*640];
      fBh[i] = *(const bf16x8*)&stg[fbh + i*640];
      fBl[i] = *(const bf16x8*)&stg[fbl + i*640];
    }
    MFMA2(acc);
  }

  // --- cross-kg reduction: [8][32][36] ---
  __syncthreads();
  {
    const int r0 = (lane>>4)<<2;
    const int c0 = lane&15;
#pragma unroll
    for (int i = 0; i < 2; ++i)
#pragma unroll
      for (int j = 0; j < 2; ++j)
#pragma unroll
        for (int g = 0; g < 4; ++g)
          fbuf[kg*1152 + (i*16 + r0 + g)*36 + j*16 + c0] = acc[i][j][g];
  }
  __syncthreads();
  const int col = lane & 31, half = lane >> 5;
#pragma unroll
  for (int rr = 0; rr < 2; ++rr) {
    const int row = (wave << 2) + (half << 1) + rr;
    float e = 0.f;
#pragma unroll
    for (int g = 0; g < 8; ++g) e += fbuf[g*1152 + row*36 + col];
    float v_ = e * rinvl[row];
    u16 h,l; bsplit(v_,h,l);
    const int s = mBase + row;
    out1h[(size_t)s*D_TOT + nBase + col] = h;
    out1l[(size_t)s*D_TOT + nBase + col] = l;
  }
}

// ================= final: out = out1 @ wo.T + bo (round-5 verbatim) =================
__global__ __launch_bounds__(512) void final_mfma(
    const u16* __restrict__ out1h, const u16* __restrict__ out1l,
    const float* __restrict__ wo, const float* __restrict__ bo,
    float* __restrict__ out)
{
  __shared__ __align__(16) u16 stage[2][30720];
  float* fbuf = (float*)stage;
  const int t = threadIdx.x, lane = t & 63, wave = t >> 6;
  const int mBase = blockIdx.y << 5, nBase = blockIdx.x << 6;
  const int kg = t >> 7, sub = t & 127;
  const int arow = sub >> 2, acol = (sub & 3) << 3;
  const int brow0 = sub >> 2, bcol0 = (sub & 3) << 3;
  const int brow1 = (sub + 128) >> 2, bcol1 = ((sub + 128) & 3) << 3;
  const int kgw = wave >> 1, wc = wave & 1;

  const u16* Agh = out1h + (size_t)(mBase+arow)*D_TOT + acol + kg*128;
  const u16* Agl = out1l + (size_t)(mBase+arow)*D_TOT + acol + kg*128;
  const float* B0 = wo + (size_t)(nBase+brow0)*D_TOT + bcol0 + kg*128;
  const float* B1 = wo + (size_t)(nBase+brow1)*D_TOT + bcol1 + kg*128;

  const int sA  = kg*7680 + arow*40 + acol;
  const int sB0 = kg*7680 + 2560 + brow0*40 + bcol0;
  const int sB1 = kg*7680 + 2560 + brow1*40 + bcol1;
  const int fa  = kgw*7680 + (lane&15)*40 + ((lane>>4)<<3);
  const int fbh = kgw*7680 + 2560 + (wc*32 + (lane&15))*40 + ((lane>>4)<<3);

  uint4 rah = *(const uint4*)Agh, ral = *(const uint4*)Agl;
  float4 b00 = *(const float4*)B0, b01 = *(const float4*)(B0 + 4);
  float4 b10 = *(const float4*)B1, b11 = *(const float4*)(B1 + 4);
  {
    uint4 bh0,bl0,bh1,bl1;
    bsplit8(b00,b01,bh0,bl0); bsplit8(b10,b11,bh1,bl1);
    *(uint4*)&stage[0][sA        ] = rah; *(uint4*)&stage[0][sA  + 1280] = ral;
    *(uint4*)&stage[0][sB0       ] = bh0; *(uint4*)&stage[0][sB0 + 2560] = bl0;
    *(uint4*)&stage[0][sB1       ] = bh1; *(uint4*)&stage[0][sB1 + 2560] = bl1;
  }
  rah = *(const uint4*)(Agh + 32); ral = *(const uint4*)(Agl + 32);
  b00 = *(const float4*)(B0 + 32); b01 = *(const float4*)(B0 + 36);
  b10 = *(const float4*)(B1 + 32); b11 = *(const float4*)(B1 + 36);

  f32x4 zero = {0.f,0.f,0.f,0.f};
  f32x4 acc[2][2] = {{zero,zero},{zero,zero}};
#pragma unroll
  for (int r = 0; r < 4; ++r) {
    __syncthreads();
    const u16* bufr = stage[r & 1];
    bf16x8 fAh[2], fAl[2], fBh[2], fBl[2];
#pragma unroll
    for (int i = 0; i < 2; ++i) {
      fAh[i] = *(const bf16x8*)&bufr[fa         + i*640];
      fAl[i] = *(const bf16x8*)&bufr[fa + 1280  + i*640];
      fBh[i] = *(const bf16x8*)&bufr[fbh        + i*640];
      fBl[i] = *(const bf16x8*)&bufr[fbh + 2560 + i*640];
    }
    if (r + 1 < 4) {
      u16* bufw = stage[(r + 1) & 1];
      uint4 bh0,bl0,bh1,bl1;
      bsplit8(b00,b01,bh0,bl0); bsplit8(b10,b11,bh1,bl1);
      *(uint4*)&bufw[sA        ] = rah; *(uint4*)&bufw[sA  + 1280] = ral;
      *(uint4*)&bufw[sB0       ] = bh0; *(uint4*)&bufw[sB0 + 2560] = bl0;
      *(uint4*)&bufw[sB1       ] = bh1; *(uint4*)&bufw[sB1 + 2560] = bl1;
      if (r + 2 < 4) {
        const int o = (r + 2) * 32;
        rah = *(const uint4*)(Agh + o); ral = *(const uint4*)(Agl + o);
        b00 = *(const float4*)(B0 + o); b01 = *(const float4*)(B0 + o + 4);
        b10 = *(const float4*)(B1 + o); b11 = *(const float4*)(B1 + o + 4);
      }
    }
    MFMA3(acc);
  }

  __syncthreads();
  {
    const int r0 = (lane>>4)<<2;
    const int c0 = wc*32 + (lane&15);
#pragma unroll
    for (int i = 0; i < 2; ++i)
#pragma unroll
      for (int j = 0; j < 2; ++j)
#pragma unroll
        for (int g = 0; g < 4; ++g)
          fbuf[kgw*2176 + (r0 + i*16 + g)*68 + c0 + j*16] = acc[i][j][g];
  }
  __syncthreads();
  const int erow = wave << 2;
  const float b = bo[nBase + lane];
#pragma unroll
  for (int r = 0; r < 4; ++r) {
    const int row = erow + r;
    float e = fbuf[row*68 + lane] + fbuf[2176 + row*68 + lane]
            + fbuf[4352 + row*68 + lane] + fbuf[6528 + row*68 + lane];
    out[(size_t)(mBase+row)*D_TOT + nBase + lane] = e + b;
  }
}

extern "C" void kernel_launch(void* const* d_in, const int* in_sizes, int n_in,
                              void* d_out, int out_size, void* d_ws, size_t ws_size,
                              hipStream_t stream)
{
  const float* x   = (const float*)d_in[0];
  const float* wq  = (const float*)d_in[1];
  const float* bq  = (const float*)d_in[2];
  const float* wk  = (const float*)d_in[3];
  const float* bk  = (const float*)d_in[4];
  const float* wv  = (const float*)d_in[5];
  const float* bv  = (const float*)d_in[6];
  const float* wo  = (const float*)d_in[7];
  const float* bo  = (const float*)d_in[8];
  const float* alpha_u = (const float*)d_in[9];
  float* out = (float*)d_out;

  u16* U = (u16*)d_ws;
  u16* Qch   = U + 0;
  u16* Kch   = U + 524288;
  u16* Kcl   = U + 1048576;
  u16* vTh   = U + 1572864;
  u16* vTl   = U + 2097152;
  u16* Eh    = U + 2621440;   // 1048576
  u16* out1h = U + 3670016;
  u16* out1l = U + 4194304;
  float* F = (float*)(U + 4718592);
  float* qnpart  = F;          // [1024][8]
  float* knpart  = F + 8192;
  float* uh2a    = F + 16384;
  float* vh2a    = F + 17408;
  float* rowpart = F + 18432;  // [1024][16]

  qkv_mfma<<<dim3(8,16,3), 512, 0, stream>>>(x, wq,bq, wk,bk, wv,bv,
      Qch, Kch, Kcl, vTh, vTl, qnpart, knpart, uh2a, vh2a);
  score_mfma<<<dim3(16,32), 512, 0, stream>>>(Qch, Kch, Kcl,
      qnpart, knpart, uh2a, vh2a, alpha_u, Eh, rowpart);
  av_mfma<<<dim3(16,32), 512, 0, stream>>>(Eh, vTh, vTl, rowpart, out1h, out1l);
  final_mfma<<<dim3(8,32), 512, 0, stream>>>(out1h, out1l, wo, bo, out);
}

// Round 8
// 42.068 us; speedup vs baseline: 1.4115x; 1.1851x over previous
//
#include <hip/hip_runtime.h>

#define S_LEN 1024
#define D_TOT 512
#define D_E   448

typedef short bf16x8 __attribute__((ext_vector_type(8)));
typedef float f32x4  __attribute__((ext_vector_type(4)));
typedef unsigned short u16;

__device__ __forceinline__ float frcp(float x) {
  float r; asm("v_rcp_f32 %0, %1" : "=v"(r) : "v"(x)); return r;
}

__device__ __forceinline__ float wave_sum64(float v) {
#pragma unroll
  for (int o = 32; o > 0; o >>= 1) v += __shfl_xor(v, o);
  return v;
}

__device__ __forceinline__ u16 bf16rne(float f) {
  unsigned u = __builtin_bit_cast(unsigned, f);
  return (u16)((u + 0x7fffu + ((u >> 16) & 1u)) >> 16);
}

// split fp32 into bf16 hi (RNE) + bf16 lo (RNE of remainder)
__device__ __forceinline__ void bsplit(float f, u16 &h, u16 &l) {
  unsigned u  = __builtin_bit_cast(unsigned, f);
  unsigned ur = u + 0x7fffu + ((u >> 16) & 1u);
  h = (u16)(ur >> 16);
  float fh = __builtin_bit_cast(float, ur & 0xffff0000u);
  float r  = f - fh;
  l = bf16rne(r);
}

__device__ __forceinline__ void bsplit8(float4 a, float4 b, uint4 &h, uint4 &l) {
  u16 h0,h1,h2,h3,h4,h5,h6,h7, l0,l1,l2,l3,l4,l5,l6,l7;
  bsplit(a.x,h0,l0); bsplit(a.y,h1,l1); bsplit(a.z,h2,l2); bsplit(a.w,h3,l3);
  bsplit(b.x,h4,l4); bsplit(b.y,h5,l5); bsplit(b.z,h6,l6); bsplit(b.w,h7,l7);
  h.x = (unsigned)h0 | ((unsigned)h1<<16); h.y = (unsigned)h2 | ((unsigned)h3<<16);
  h.z = (unsigned)h4 | ((unsigned)h5<<16); h.w = (unsigned)h6 | ((unsigned)h7<<16);
  l.x = (unsigned)l0 | ((unsigned)l1<<16); l.y = (unsigned)l2 | ((unsigned)l3<<16);
  l.z = (unsigned)l4 | ((unsigned)l5<<16); l.w = (unsigned)l6 | ((unsigned)l7<<16);
}

__device__ __forceinline__ uint4 rne8(float4 a, float4 b) {
  uint4 h;
  h.x = (unsigned)bf16rne(a.x) | ((unsigned)bf16rne(a.y)<<16);
  h.y = (unsigned)bf16rne(a.z) | ((unsigned)bf16rne(a.w)<<16);
  h.z = (unsigned)bf16rne(b.x) | ((unsigned)bf16rne(b.y)<<16);
  h.w = (unsigned)bf16rne(b.z) | ((unsigned)bf16rne(b.w)<<16);
  return h;
}

// 2-term split MFMA: A-hi x (Bh + Bl)
#define MFMA2(ACC)                                                                              \
  _Pragma("unroll") for (int i_ = 0; i_ < 2; ++i_)                                              \
  _Pragma("unroll") for (int j_ = 0; j_ < 2; ++j_) {                                            \
    ACC[i_][j_] = __builtin_amdgcn_mfma_f32_16x16x32_bf16(fAh[i_], fBh[j_], ACC[i_][j_],0,0,0); \
    ACC[i_][j_] = __builtin_amdgcn_mfma_f32_16x16x32_bf16(fAh[i_], fBl[j_], ACC[i_][j_],0,0,0); \
  }

// ================= QKV: q/k/v = x @ W.T + b (x hi-only, W hi/lo, MFMA2) =================
// 64x64 tile, 8 waves = 2(kg) x 2(wr) x 2(wc), BK=32, dbuf LDS 61440B -> 2 blocks/CU.
__global__ __launch_bounds__(512,4) void qkv_mfma(
    const float* __restrict__ x,
    const float* __restrict__ wq, const float* __restrict__ bq,
    const float* __restrict__ wk, const float* __restrict__ bk,
    const float* __restrict__ wv, const float* __restrict__ bv,
    u16* __restrict__ Qch,
    u16* __restrict__ Kch, u16* __restrict__ Kcl,
    u16* __restrict__ vTh, u16* __restrict__ vTl,
    float* __restrict__ qnpart, float* __restrict__ knpart,
    float* __restrict__ uh2a, float* __restrict__ vh2a)
{
  __shared__ __align__(16) u16 stage[2][15360];   // per buf: [2 kg][Ah|Bh|Bl][64][40]
  float* fbuf = (float*)stage;                    // [2 kg][64][68]
  const int z = blockIdx.z;
  const float* W; const float* bias;
  if (z == 0)      { W = wq; bias = bq; }
  else if (z == 1) { W = wk; bias = bk; }
  else             { W = wv; bias = bv; }
  const int mBase = blockIdx.y << 6, nBase = blockIdx.x << 6;
  const int t = threadIdx.x, lane = t & 63, wave = t >> 6;
  const int kg = t >> 8, sub = t & 255;
  const int srow = sub >> 2, scol = (sub & 3) << 3;
  const int kgw = wave >> 2, wr = (wave >> 1) & 1, wc = wave & 1;

  const float* Ag = x + (size_t)(mBase + srow) * D_TOT + scol + kg * 256;
  const float* Bg = W + (size_t)(nBase + srow) * D_TOT + scol + kg * 256;

  const int sb = kg * 7680 + srow * 40 + scol;
  const int fa = kgw * 7680 + (wr * 32 + (lane & 15)) * 40 + ((lane >> 4) << 3);
  const int fb = kgw * 7680 + 2560 + (wc * 32 + (lane & 15)) * 40 + ((lane >> 4) << 3);

  float4 a0 = *(const float4*)Ag, a1 = *(const float4*)(Ag + 4);
  float4 b0 = *(const float4*)Bg, b1 = *(const float4*)(Bg + 4);
  {
    uint4 hB,lB; bsplit8(b0,b1,hB,lB);
    *(uint4*)&stage[0][sb       ] = rne8(a0,a1);
    *(uint4*)&stage[0][sb + 2560] = hB;
    *(uint4*)&stage[0][sb + 5120] = lB;
  }
  a0 = *(const float4*)(Ag + 32); a1 = *(const float4*)(Ag + 36);
  b0 = *(const float4*)(Bg + 32); b1 = *(const float4*)(Bg + 36);

  f32x4 zero = {0.f,0.f,0.f,0.f};
  f32x4 acc[2][2] = {{zero,zero},{zero,zero}};
#pragma unroll
  for (int r = 0; r < 8; ++r) {
    __syncthreads();
    const u16* bufr = stage[r & 1];
    bf16x8 fAh[2], fBh[2], fBl[2];
#pragma unroll
    for (int i = 0; i < 2; ++i) {
      fAh[i] = *(const bf16x8*)&bufr[fa        + i*640];
      fBh[i] = *(const bf16x8*)&bufr[fb        + i*640];
      fBl[i] = *(const bf16x8*)&bufr[fb + 2560 + i*640];
    }
    if (r + 1 < 8) {
      u16* bufw = stage[(r + 1) & 1];
      uint4 hB,lB; bsplit8(b0,b1,hB,lB);
      *(uint4*)&bufw[sb       ] = rne8(a0,a1);
      *(uint4*)&bufw[sb + 2560] = hB;
      *(uint4*)&bufw[sb + 5120] = lB;
      if (r + 2 < 8) {
        const int o = (r + 2) * 32;
        a0 = *(const float4*)(Ag + o); a1 = *(const float4*)(Ag + o + 4);
        b0 = *(const float4*)(Bg + o); b1 = *(const float4*)(Bg + o + 4);
      }
    }
    MFMA2(acc);
  }

  // --- cross-kg reduction (single round-trip) ---
  __syncthreads();
  {
    const int r0 = wr*32 + ((lane>>4)<<2);
    const int c0 = wc*32 + (lane&15);
#pragma unroll
    for (int i = 0; i < 2; ++i)
#pragma unroll
      for (int j = 0; j < 2; ++j)
#pragma unroll
        for (int g = 0; g < 4; ++g)
          fbuf[kgw*4352 + (r0 + i*16 + g)*68 + c0 + j*16] = acc[i][j][g];
  }
  __syncthreads();
  const int erow = wave << 3;
  float val[8];
  {
    const float b = bias[nBase + lane];
#pragma unroll
    for (int r = 0; r < 8; ++r)
      val[r] = fbuf[(erow+r)*68 + lane] + fbuf[4352 + (erow+r)*68 + lane] + b;
  }

  if (z == 2) {
    u16 hh[8], ll[8];
#pragma unroll
    for (int r = 0; r < 8; ++r) bsplit(val[r], hh[r], ll[r]);
    const size_t off = (size_t)(nBase + lane) * S_LEN + mBase + erow;
    ushort4 p0{hh[0],hh[1],hh[2],hh[3]}, p1{hh[4],hh[5],hh[6],hh[7]};
    ushort4 q0{ll[0],ll[1],ll[2],ll[3]}, q1{ll[4],ll[5],ll[6],ll[7]};
    *(ushort4*)(vTh + off) = p0; *(ushort4*)(vTh + off + 4) = p1;
    *(ushort4*)(vTl + off) = q0; *(ushort4*)(vTl + off + 4) = q1;
  } else if (z == 1) {
    if (blockIdx.x < 7) {
#pragma unroll
      for (int r = 0; r < 8; ++r) {
        const int s = mBase + erow + r;
        u16 h,l; bsplit(val[r],h,l);
        Kch[(size_t)s*D_TOT + nBase + lane] = h;
        Kcl[(size_t)s*D_TOT + nBase + lane] = l;
        float p = wave_sum64(val[r]*val[r]);
        if (lane == 0) knpart[s*8 + blockIdx.x] = p;
      }
    } else {
#pragma unroll
      for (int r = 0; r < 8; ++r) {
        const int s = mBase + erow + r;
        float n2 = wave_sum64(val[r]*val[r]);
        float nn = sqrtf(n2);
        float n  = fmaxf(nn, 1e-5f);
        float e2n = __expf(2.f*n);
        float th  = 1.f - 2.f*frcp(e2n + 1.f);
        float rn  = frcp(n);
        float pn  = th * nn * rn;
        float scale = fminf(0.999f * frcp(fmaxf(pn, 1e-5f)), 1.f);
        float u = th * rn * scale * val[r];
        float un = pn * scale;
        u16 h,l; bsplit(u,h,l);
        Kch[(size_t)s*D_TOT + nBase + lane] = h;
        Kcl[(size_t)s*D_TOT + nBase + lane] = l;
        if (lane == 0) vh2a[s] = un*un;
      }
    }
  } else {
    if (blockIdx.x < 7) {
#pragma unroll
      for (int r = 0; r < 8; ++r) {
        const int s = mBase + erow + r;
        Qch[(size_t)s*D_TOT + nBase + lane] = bf16rne(val[r]);
        float p = wave_sum64(val[r]*val[r]);
        if (lane == 0) qnpart[s*8 + blockIdx.x] = p;
      }
    } else {
#pragma unroll
      for (int r = 0; r < 8; ++r) {
        const int s = mBase + erow + r;
        float n2 = wave_sum64(val[r]*val[r]);
        float nn = sqrtf(n2);
        float n  = fmaxf(nn, 1e-5f);
        float e2n = __expf(2.f*n);
        float th  = 1.f - 2.f*frcp(e2n + 1.f);
        float rn  = frcp(n);
        float pn  = th * nn * rn;
        float scale = fminf(0.999f * frcp(fmaxf(pn, 1e-5f)), 1.f);
        float u = th * rn * scale * val[r];
        float un = pn * scale;
        Qch[(size_t)s*D_TOT + nBase + lane] = bf16rne(u);
        if (lane == 0) uh2a[s] = un*un;
      }
    }
  }
}

// ================= scores + exp + partial rowsums (round-5 structure) =================
__global__ __launch_bounds__(512,4) void score_mfma(
    const u16* __restrict__ Qch,
    const u16* __restrict__ Kch, const u16* __restrict__ Kcl,
    const float* __restrict__ qnpart, const float* __restrict__ knpart,
    const float* __restrict__ uh2a, const float* __restrict__ vh2a,
    const float* __restrict__ alpha_u,
    u16* __restrict__ Eh, float* __restrict__ rowpart)
{
  __shared__ __align__(16) char shm_[69632];
  __shared__ float rowscal[256];    // qn[64] kn[64] u2[64] v2[64]
  u16* stg = (u16*)shm_;
  float* fbuf = (float*)shm_;
  const int t = threadIdx.x, lane = t & 63, wave = t >> 6;
  const int mBase = blockIdx.y << 6, nBase = blockIdx.x << 6;
  if (t < 64) {
    float s_ = 0.f;
#pragma unroll
    for (int c = 0; c < 7; ++c) s_ += qnpart[(mBase+t)*8 + c];
    rowscal[t] = s_;
  } else if (t < 128) {
    float s_ = 0.f;
#pragma unroll
    for (int c = 0; c < 7; ++c) s_ += knpart[(nBase+t-64)*8 + c];
    rowscal[t] = s_;
  } else if (t < 192) rowscal[t] = uh2a[mBase + t - 128];
  else if (t < 256)   rowscal[t] = vh2a[nBase + t - 192];

  const int kg = t >> 8, sub = t & 255;
  const int srow = sub >> 2, scol = (sub & 3) << 3;
  const int kgw = wave >> 2, wr = (wave >> 1) & 1, wc = wave & 1;
  const u16* Agh = Qch + (size_t)(mBase+srow)*D_TOT + scol;
  const u16* Bgh = Kch + (size_t)(nBase+srow)*D_TOT + scol;
  const u16* Bgl = Kcl + (size_t)(nBase+srow)*D_TOT + scol;

  const int sb  = kg * 7680 + srow * 40 + scol;
  const int fa  = kgw * 7680 + (wr * 32 + (lane & 15)) * 40 + ((lane >> 4) << 3);
  const int fbh = kgw * 7680 + 2560 + (wc * 32 + (lane & 15)) * 40 + ((lane >> 4) << 3);

  int kb = kg * 224;
  uint4 rAh = *(const uint4*)(Agh + kb);
  uint4 rBh = *(const uint4*)(Bgh + kb), rBl = *(const uint4*)(Bgl + kb);
  *(uint4*)&stg[sb       ] = rAh;
  *(uint4*)&stg[sb + 2560] = rBh;
  *(uint4*)&stg[sb + 5120] = rBl;
  kb = kg * 224 + 32;
  rAh = *(const uint4*)(Agh + kb);
  rBh = *(const uint4*)(Bgh + kb); rBl = *(const uint4*)(Bgl + kb);

  f32x4 zero = {0.f,0.f,0.f,0.f};
  f32x4 accE[2][2] = {{zero,zero},{zero,zero}};
  f32x4 accH[2][2] = {{zero,zero},{zero,zero}};
#pragma unroll
  for (int r = 0; r < 8; ++r) {
    __syncthreads();
    const u16* bufr = stg + (r & 1) * 15360;
    bf16x8 fAh[2], fBh[2], fBl[2];
#pragma unroll
    for (int i = 0; i < 2; ++i) {
      fAh[i] = *(const bf16x8*)&bufr[fa         + i*640];
      fBh[i] = *(const bf16x8*)&bufr[fbh        + i*640];
      fBl[i] = *(const bf16x8*)&bufr[fbh + 2560 + i*640];
    }
    if (r + 1 < 8) {
      u16* bufw = stg + ((r + 1) & 1) * 15360;
      *(uint4*)&bufw[sb       ] = rAh;
      *(uint4*)&bufw[sb + 2560] = rBh;
      *(uint4*)&bufw[sb + 5120] = rBl;
      if (r + 2 < 8) {
        const int o = (r + 2 < 7) ? (kg*224 + (r+2)*32) : (448 + kg*32);
        rAh = *(const uint4*)(Agh + o);
        rBh = *(const uint4*)(Bgh + o); rBl = *(const uint4*)(Bgl + o);
      }
    }
    if (r < 7) { MFMA2(accE) } else { MFMA2(accH) }
  }

  __syncthreads();
  {
    const int r0 = wr*32 + ((lane>>4)<<2);
    const int c0 = wc*32 + (lane&15);
#pragma unroll
    for (int i = 0; i < 2; ++i)
#pragma unroll
      for (int j = 0; j < 2; ++j)
#pragma unroll
        for (int g = 0; g < 4; ++g) {
          fbuf[       kgw*4352 + (r0 + i*16 + g)*68 + c0 + j*16] = accE[i][j][g];
          fbuf[8704 + kgw*4352 + (r0 + i*16 + g)*68 + c0 + j*16] = accH[i][j][g];
        }
  }
  __syncthreads();
  const int erow = wave << 3;
  float eE[8], eH[8];
#pragma unroll
  for (int r = 0; r < 8; ++r) {
    eE[r] = fbuf[(erow+r)*68 + lane] + fbuf[4352 + (erow+r)*68 + lane];
    eH[r] = fbuf[8704 + (erow+r)*68 + lane] + fbuf[8704 + 4352 + (erow+r)*68 + lane];
  }

  const float alpha = __logf(1.f + __expf(alpha_u[0]));
  const float inv_s = 0.04419417382415922f;   // 1/sqrt(512)
  const float knl = rowscal[64 + lane], v2 = rowscal[192 + lane];
#pragma unroll
  for (int r = 0; r < 8; ++r) {
    const int s = mBase + erow + r;
    const float qns = rowscal[erow + r], u2 = rowscal[128 + erow + r];
    float de   = qns + knl - 2.f * eE[r];
    float dH   = eH[r];
    float Ac   = 1.f - 2.f*dH + v2;
    float Bc   = 1.f - u2;
    float num2 = Ac*Ac*u2 + Bc*Bc*v2 - 2.f*Ac*Bc*dH;
    float den  = fmaxf(1.f - 2.f*dH + u2*v2, 1e-5f);
    float frac = sqrtf(fmaxf(num2, 0.f)) * frcp(den);
    float nrm  = fminf(frac, 0.999f);
    float dh_  = __logf((1.f + nrm) * frcp(1.f - nrm));   // = 2*atanh(nrm)
    float dist = de + alpha * dh_ * dh_;
    float lg   = fminf(fmaxf(-dist * inv_s, -50.f), 0.f);
    float e    = __expf(lg);
    Eh[(size_t)s*S_LEN + nBase + lane] = bf16rne(e);
    float rs = wave_sum64(e);
    if (lane == 0) rowpart[s*16 + blockIdx.x] = rs;
  }
}

// ================= attn @ V: 32x64 tile, kg4, single-buf 51200B -> 2 blocks/CU =================
__global__ __launch_bounds__(512,4) void av_mfma(
    const u16* __restrict__ Eh,
    const u16* __restrict__ vTh, const u16* __restrict__ vTl,
    const float* __restrict__ rowpart,
    u16* __restrict__ out1h)
{
  __shared__ __align__(16) u16 stg[25600];   // [4 kg][A 1280 | Bh 2560 | Bl 2560]
  __shared__ float rinvl[32];
  float* fbuf = (float*)stg;                 // [4 kg][32][68]
  const int t = threadIdx.x, lane = t & 63, wave = t >> 6;
  const int mBase = blockIdx.y << 5, nBase = blockIdx.x << 6;
  if (t < 32) {
    float s_ = 0.f;
#pragma unroll
    for (int c = 0; c < 16; ++c) s_ += rowpart[(mBase+t)*16 + c];
    rinvl[t] = 1.f / s_;
  }
  const int kg = t >> 7, sub = t & 127;
  const int arow = sub >> 2, acol = (sub & 3) << 3;
  const int brow0 = sub >> 2, bcol0 = (sub & 3) << 3;
  const int brow1 = (sub + 128) >> 2, bcol1 = ((sub + 128) & 3) << 3;
  const int kgw = wave >> 1, wc = wave & 1;

  const u16* Ag  = Eh  + (size_t)(mBase+arow)*S_LEN + acol + kg*256;
  const u16* B0h = vTh + (size_t)(nBase+brow0)*S_LEN + bcol0 + kg*256;
  const u16* B0l = vTl + (size_t)(nBase+brow0)*S_LEN + bcol0 + kg*256;
  const u16* B1h = vTh + (size_t)(nBase+brow1)*S_LEN + bcol1 + kg*256;
  const u16* B1l = vTl + (size_t)(nBase+brow1)*S_LEN + bcol1 + kg*256;

  const int sA  = kg*6400 + arow*40 + acol;
  const int sB0 = kg*6400 + 1280 + brow0*40 + bcol0;
  const int sB1 = kg*6400 + 1280 + brow1*40 + bcol1;
  const int fa  = kgw*6400 + (lane&15)*40 + ((lane>>4)<<3);
  const int fbh = kgw*6400 + 1280 + (wc*32 + (lane&15))*40 + ((lane>>4)<<3);

  uint4 rA = *(const uint4*)Ag;
  uint4 rb0h = *(const uint4*)B0h, rb0l = *(const uint4*)B0l;
  uint4 rb1h = *(const uint4*)B1h, rb1l = *(const uint4*)B1l;

  f32x4 zero = {0.f,0.f,0.f,0.f};
  f32x4 acc[2][2] = {{zero,zero},{zero,zero}};
#pragma unroll
  for (int r = 0; r < 8; ++r) {
    __syncthreads();
    *(uint4*)&stg[sA        ] = rA;
    *(uint4*)&stg[sB0       ] = rb0h; *(uint4*)&stg[sB0 + 2560] = rb0l;
    *(uint4*)&stg[sB1       ] = rb1h; *(uint4*)&stg[sB1 + 2560] = rb1l;
    if (r + 1 < 8) {
      const int o = (r + 1) * 32;
      rA = *(const uint4*)(Ag + o);
      rb0h = *(const uint4*)(B0h + o); rb0l = *(const uint4*)(B0l + o);
      rb1h = *(const uint4*)(B1h + o); rb1l = *(const uint4*)(B1l + o);
    }
    __syncthreads();
    bf16x8 fAh[2], fBh[2], fBl[2];
#pragma unroll
    for (int i = 0; i < 2; ++i) {
      fAh[i] = *(const bf16x8*)&stg[fa         + i*640];
      fBh[i] = *(const bf16x8*)&stg[fbh        + i*640];
      fBl[i] = *(const bf16x8*)&stg[fbh + 2560 + i*640];
    }
    MFMA2(acc);
  }

  __syncthreads();
  {
    const int r0 = (lane>>4)<<2;
    const int c0 = wc*32 + (lane&15);
#pragma unroll
    for (int i = 0; i < 2; ++i)
#pragma unroll
      for (int j = 0; j < 2; ++j)
#pragma unroll
        for (int g = 0; g < 4; ++g)
          fbuf[kgw*2176 + (r0 + i*16 + g)*68 + c0 + j*16] = acc[i][j][g];
  }
  __syncthreads();
  const int erow = wave << 2;
#pragma unroll
  for (int r = 0; r < 4; ++r) {
    const int row = erow + r;
    float e = fbuf[row*68 + lane] + fbuf[2176 + row*68 + lane]
            + fbuf[4352 + row*68 + lane] + fbuf[6528 + row*68 + lane];
    float v_ = e * rinvl[row];
    const int s = mBase + row;
    out1h[(size_t)s*D_TOT + nBase + lane] = bf16rne(v_);
  }
}

// ================= final: out = out1h @ wo.T + bo (A hi-only, wo split in staging) =================
// 32x64 tile, kg4 (K=128 each), 4 steps of 32, single-buf 51200B -> 2 blocks/CU.
__global__ __launch_bounds__(512,4) void final_mfma(
    const u16* __restrict__ out1h,
    const float* __restrict__ wo, const float* __restrict__ bo,
    float* __restrict__ out)
{
  __shared__ __align__(16) u16 stg[25600];   // [4 kg][A 1280 | Bh 2560 | Bl 2560]
  float* fbuf = (float*)stg;
  const int t = threadIdx.x, lane = t & 63, wave = t >> 6;
  const int mBase = blockIdx.y << 5, nBase = blockIdx.x << 6;
  const int kg = t >> 7, sub = t & 127;
  const int arow = sub >> 2, acol = (sub & 3) << 3;
  const int brow0 = sub >> 2, bcol0 = (sub & 3) << 3;
  const int brow1 = (sub + 128) >> 2, bcol1 = ((sub + 128) & 3) << 3;
  const int kgw = wave >> 1, wc = wave & 1;

  const u16* Ag = out1h + (size_t)(mBase+arow)*D_TOT + acol + kg*128;
  const float* B0 = wo + (size_t)(nBase+brow0)*D_TOT + bcol0 + kg*128;
  const float* B1 = wo + (size_t)(nBase+brow1)*D_TOT + bcol1 + kg*128;

  const int sA  = kg*6400 + arow*40 + acol;
  const int sB0 = kg*6400 + 1280 + brow0*40 + bcol0;
  const int sB1 = kg*6400 + 1280 + brow1*40 + bcol1;
  const int fa  = kgw*6400 + (lane&15)*40 + ((lane>>4)<<3);
  const int fbh = kgw*6400 + 1280 + (wc*32 + (lane&15))*40 + ((lane>>4)<<3);

  uint4 rA = *(const uint4*)Ag;
  float4 b00 = *(const float4*)B0, b01 = *(const float4*)(B0 + 4);
  float4 b10 = *(const float4*)B1, b11 = *(const float4*)(B1 + 4);

  f32x4 zero = {0.f,0.f,0.f,0.f};
  f32x4 acc[2][2] = {{zero,zero},{zero,zero}};
#pragma unroll
  for (int r = 0; r < 4; ++r) {
    __syncthreads();
    uint4 bh0,bl0,bh1,bl1;
    bsplit8(b00,b01,bh0,bl0); bsplit8(b10,b11,bh1,bl1);
    *(uint4*)&stg[sA        ] = rA;
    *(uint4*)&stg[sB0       ] = bh0; *(uint4*)&stg[sB0 + 2560] = bl0;
    *(uint4*)&stg[sB1       ] = bh1; *(uint4*)&stg[sB1 + 2560] = bl1;
    if (r + 1 < 4) {
      const int o = (r + 1) * 32;
      rA = *(const uint4*)(Ag + o);
      b00 = *(const float4*)(B0 + o); b01 = *(const float4*)(B0 + o + 4);
      b10 = *(const float4*)(B1 + o); b11 = *(const float4*)(B1 + o + 4);
    }
    __syncthreads();
    bf16x8 fAh[2], fBh[2], fBl[2];
#pragma unroll
    for (int i = 0; i < 2; ++i) {
      fAh[i] = *(const bf16x8*)&stg[fa         + i*640];
      fBh[i] = *(const bf16x8*)&stg[fbh        + i*640];
      fBl[i] = *(const bf16x8*)&stg[fbh + 2560 + i*640];
    }
    MFMA2(acc);
  }

  __syncthreads();
  {
    const int r0 = (lane>>4)<<2;
    const int c0 = wc*32 + (lane&15);
#pragma unroll
    for (int i = 0; i < 2; ++i)
#pragma unroll
      for (int j = 0; j < 2; ++j)
#pragma unroll
        for (int g = 0; g < 4; ++g)
          fbuf[kgw*2176 + (r0 + i*16 + g)*68 + c0 + j*16] = acc[i][j][g];
  }
  __syncthreads();
  const int erow = wave << 2;
  const float b = bo[nBase + lane];
#pragma unroll
  for (int r = 0; r < 4; ++r) {
    const int row = erow + r;
    float e = fbuf[row*68 + lane] + fbuf[2176 + row*68 + lane]
            + fbuf[4352 + row*68 + lane] + fbuf[6528 + row*68 + lane];
    out[(size_t)(mBase+row)*D_TOT + nBase + lane] = e + b;
  }
}

extern "C" void kernel_launch(void* const* d_in, const int* in_sizes, int n_in,
                              void* d_out, int out_size, void* d_ws, size_t ws_size,
                              hipStream_t stream)
{
  const float* x   = (const float*)d_in[0];
  const float* wq  = (const float*)d_in[1];
  const float* bq  = (const float*)d_in[2];
  const float* wk  = (const float*)d_in[3];
  const float* bk  = (const float*)d_in[4];
  const float* wv  = (const float*)d_in[5];
  const float* bv  = (const float*)d_in[6];
  const float* wo  = (const float*)d_in[7];
  const float* bo  = (const float*)d_in[8];
  const float* alpha_u = (const float*)d_in[9];
  float* out = (float*)d_out;

  u16* U = (u16*)d_ws;
  u16* Qch   = U + 0;
  u16* Kch   = U + 524288;
  u16* Kcl   = U + 1048576;
  u16* vTh   = U + 1572864;
  u16* vTl   = U + 2097152;
  u16* Eh    = U + 2621440;   // 1048576
  u16* out1h = U + 3670016;
  float* F = (float*)(U + 4194304);
  float* qnpart  = F;          // [1024][8]
  float* knpart  = F + 8192;
  float* uh2a    = F + 16384;
  float* vh2a    = F + 17408;
  float* rowpart = F + 18432;  // [1024][16]

  qkv_mfma<<<dim3(8,16,3), 512, 0, stream>>>(x, wq,bq, wk,bk, wv,bv,
      Qch, Kch, Kcl, vTh, vTl, qnpart, knpart, uh2a, vh2a);
  score_mfma<<<dim3(16,16), 512, 0, stream>>>(Qch, Kch, Kcl,
      qnpart, knpart, uh2a, vh2a, alpha_u, Eh, rowpart);
  av_mfma<<<dim3(8,32), 512, 0, stream>>>(Eh, vTh, vTl, rowpart, out1h);
  final_mfma<<<dim3(8,32), 512, 0, stream>>>(out1h, wo, bo, out);
}